// Round 1
// baseline (18073.662 us; speedup 1.0000x reference)
//
#include <hip/hip_runtime.h>

#define NL 12
#define Dm 768
#define NH 12
#define HD 64
#define NV 50257
#define NB 2
#define NT 1024
#define MROWS (NB * NT)   // 2048

typedef __attribute__((ext_vector_type(8))) short bf16x8;
typedef __attribute__((ext_vector_type(4))) float f32x4;

// fp32 -> (hi, lo) bf16 split.  hi = truncated top 16 bits (exact),
// lo = round-half-up bf16 of the residual.  |err| ~ 2^-17 |x|; the dropped
// lo*lo MFMA term adds ~2^-18.  Net product error ~2^-16 relative.
__device__ __forceinline__ void split2(float f, unsigned short& h, unsigned short& l) {
    unsigned u = __float_as_uint(f);
    h = (unsigned short)(u >> 16);
    float lf = f - __uint_as_float(u & 0xffff0000u);
    unsigned lu = __float_as_uint(lf);
    l = (unsigned short)((lu + 0x8000u) >> 16);
}

__device__ __forceinline__ float gelu_exact(float v) {
    return 0.5f * v * (1.0f + erff(v * 0.70710678118654752f));
}

// Load one 16x32 MFMA fragment row: lane holds 8 contiguous bf16 at k=8*lg.
// Row stride 36 ushorts (72 B): 8B-aligned b64 reads, bank-conflict-free
// (18*r mod 32 hits all 16 residues for r=0..15).
__device__ __forceinline__ bf16x8 ldfrag(const unsigned short* rowp, int lg) {
    union { ushort4 u[2]; bf16x8 v; } t;
    t.u[0] = *(const ushort4*)(rowp + 8 * lg);
    t.u[1] = *(const ushort4*)(rowp + 8 * lg + 4);
    return t.v;
}

// ---------------------------------------------------------------- embedding
__global__ void embed_kernel(const int* __restrict__ ids,
                             const float* __restrict__ wte,
                             const float* __restrict__ wpe,
                             float* __restrict__ x) {
    int row = blockIdx.x;
    int t = row & (NT - 1);
    int id = ids[row];
    const float* src = wte + (size_t)id * Dm;
    const float* pos = wpe + (size_t)t * Dm;
    float* dst = x + (size_t)row * Dm;
    for (int i = threadIdx.x; i < Dm; i += 256)
        dst[i] = src[i] + pos[i];
}

// ---------------------------------------------------------------- layernorm
__global__ void ln_kernel(const float* __restrict__ x,
                          const float* __restrict__ g,
                          const float* __restrict__ b,
                          float* __restrict__ out) {
    int row = blockIdx.x;
    int tid = threadIdx.x;
    const float* xr = x + (size_t)row * Dm;
    float v0 = xr[tid];
    float v1 = xr[tid + 256];
    float v2 = xr[tid + 512];
    float s = v0 + v1 + v2;
    #pragma unroll
    for (int off = 32; off; off >>= 1) s += __shfl_xor(s, off);
    __shared__ float red[4];
    __shared__ float red2[4];
    int wid = tid >> 6;
    if ((tid & 63) == 0) red[wid] = s;
    __syncthreads();
    float mean = (red[0] + red[1] + red[2] + red[3]) * (1.0f / Dm);
    float d0 = v0 - mean, d1 = v1 - mean, d2 = v2 - mean;
    float sq = d0 * d0 + d1 * d1 + d2 * d2;
    #pragma unroll
    for (int off = 32; off; off >>= 1) sq += __shfl_xor(sq, off);
    if ((tid & 63) == 0) red2[wid] = sq;
    __syncthreads();
    float var = (red2[0] + red2[1] + red2[2] + red2[3]) * (1.0f / Dm);
    float rstd = rsqrtf(var + 1e-5f);
    float* o = out + (size_t)row * Dm;
    o[tid]       = d0 * rstd * g[tid]       + b[tid];
    o[tid + 256] = d1 * rstd * g[tid + 256] + b[tid + 256];
    o[tid + 512] = d2 * rstd * g[tid + 512] + b[tid + 512];
}

// ---------------------------------------------------------------- MFMA GEMM
// C[M,N] = act(A[M,K] @ W + bias) + resid, fp32 in/out, bf16-split compute:
// A = Ah + Al, W = Bh + Bl (bf16), C ~= Ah*Bh + Al*Bh + Ah*Bl (3 MFMA passes).
// TRANSB=false: W is [K,N] row-major (layer weights), transposed through an
//   fp32 LDS buffer. TRANSB=true: W is [N,K] row-major (wte for lm-head).
// Block = 256 threads = 4 waves (2x2), tile TM x TN, BK = 32 fp32.
// Wave tile (TM/2)x(TN/2); 16x16x32 MFMA frags; layouts per m89/m92:
//   A frag: row = lane&15, k = 8*(lane>>4)+j (8 contiguous)
//   B frag: col = lane&15, same k map
//   C frag: col = lane&15, row = 4*(lane>>4)+reg
template <int TM, int TN, bool TRANSB>
__global__ __launch_bounds__(256, 3)
void gemm_mfma(const float* __restrict__ A,
               const float* __restrict__ W,
               const float* __restrict__ bias,
               const float* __restrict__ resid,
               float* __restrict__ C,
               int M, int K, int N, int act) {
    constexpr int FRM = TM / 32;          // 16x16 frags per wave (M)
    constexpr int FRN = TN / 32;          // 16x16 frags per wave (N)
    constexpr int CPA = TM / 32;          // float4 chunks / thread, A stage
    constexpr int CPW = TN / 32;          // float4 chunks / thread, B stage
    constexpr int WLD = TN + 4;           // fp32 staging row stride (16B-aligned)

    __shared__ __align__(16) unsigned short Ah[TM][36];
    __shared__ __align__(16) unsigned short Al[TM][36];
    __shared__ __align__(16) unsigned short Bh[TN][36];
    __shared__ __align__(16) unsigned short Bl[TN][36];
    __shared__ __align__(16) float Wst[TRANSB ? 4 : 32 * WLD];

    const int tid = threadIdx.x;
    const int lane = tid & 63;
    const int wv = tid >> 6;
    const int wm = wv >> 1, wn = wv & 1;
    const int lr = lane & 15, lg = lane >> 4;
    const int m0 = blockIdx.y * TM;
    const int n0 = blockIdx.x * TN;

    f32x4 acc[FRM][FRN];
    #pragma unroll
    for (int i = 0; i < FRM; ++i)
        #pragma unroll
        for (int j = 0; j < FRN; ++j)
            #pragma unroll
            for (int e = 0; e < 4; ++e) acc[i][j][e] = 0.0f;

    // transpose-phase map (!TRANSB): thread owns one column, TN/8 contig k.
    // Reads: addr/4 = 4*k + col -> 64 consecutive dwords per wave: conflict-free.
    const int ttn = tid & (TN - 1);
    const int tks = (tid / TN) * (TN / 8);

    for (int k0 = 0; k0 < K; k0 += 32) {
        // ---- stage A: coalesced float4 reads, packed b64 bf16 writes
        #pragma unroll
        for (int i = 0; i < CPA; ++i) {
            int ci = tid * CPA + i;
            int r = ci >> 3, kc = (ci & 7) << 2;
            float4 v = *(const float4*)(A + (size_t)(m0 + r) * K + k0 + kc);
            ushort4 hh, ll;
            split2(v.x, hh.x, ll.x); split2(v.y, hh.y, ll.y);
            split2(v.z, hh.z, ll.z); split2(v.w, hh.w, ll.w);
            *(ushort4*)&Ah[r][kc] = hh;
            *(ushort4*)&Al[r][kc] = ll;
        }
        if constexpr (TRANSB) {
            // W is [N,K]: same pattern as A, guarded for the N tail (lm-head)
            #pragma unroll
            for (int i = 0; i < CPW; ++i) {
                int ci = tid * CPW + i;
                int r = ci >> 3, kc = (ci & 7) << 2;
                float4 v = make_float4(0.f, 0.f, 0.f, 0.f);
                if (n0 + r < N)
                    v = *(const float4*)(W + (size_t)(n0 + r) * K + k0 + kc);
                ushort4 hh, ll;
                split2(v.x, hh.x, ll.x); split2(v.y, hh.y, ll.y);
                split2(v.z, hh.z, ll.z); split2(v.w, hh.w, ll.w);
                *(ushort4*)&Bh[r][kc] = hh;
                *(ushort4*)&Bl[r][kc] = ll;
            }
            __syncthreads();
        } else {
            // W is [K,N]: coalesced float4 into fp32 LDS, then LDS transpose
            #pragma unroll
            for (int i = 0; i < CPW; ++i) {
                int ci = tid * CPW + i;
                int kk = ci / (TN / 4);
                int nc = (ci % (TN / 4)) << 2;
                *(float4*)&Wst[kk * WLD + nc] =
                    *(const float4*)(W + (size_t)(k0 + kk) * N + n0 + nc);
            }
            __syncthreads();
            #pragma unroll
            for (int j4 = 0; j4 < TN / 32; ++j4) {
                ushort4 hh, ll;
                float w0 = Wst[(tks + j4 * 4 + 0) * WLD + ttn];
                float w1 = Wst[(tks + j4 * 4 + 1) * WLD + ttn];
                float w2 = Wst[(tks + j4 * 4 + 2) * WLD + ttn];
                float w3 = Wst[(tks + j4 * 4 + 3) * WLD + ttn];
                split2(w0, hh.x, ll.x); split2(w1, hh.y, ll.y);
                split2(w2, hh.z, ll.z); split2(w3, hh.w, ll.w);
                *(ushort4*)&Bh[ttn][tks + j4 * 4] = hh;
                *(ushort4*)&Bl[ttn][tks + j4 * 4] = ll;
            }
            __syncthreads();
        }

        // ---- MFMA: 3 passes (hi*hi, lo*hi, hi*lo) into fp32 acc
        bf16x8 afh[FRM], afl[FRM];
        #pragma unroll
        for (int mb = 0; mb < FRM; ++mb) {
            int r = wm * (TM / 2) + mb * 16 + lr;
            afh[mb] = ldfrag(&Ah[r][0], lg);
            afl[mb] = ldfrag(&Al[r][0], lg);
        }
        #pragma unroll
        for (int nb = 0; nb < FRN; ++nb) {
            int cB = wn * (TN / 2) + nb * 16 + lr;
            bf16x8 bfh = ldfrag(&Bh[cB][0], lg);
            bf16x8 bfl = ldfrag(&Bl[cB][0], lg);
            #pragma unroll
            for (int mb = 0; mb < FRM; ++mb) {
                acc[mb][nb] = __builtin_amdgcn_mfma_f32_16x16x32_bf16(afh[mb], bfh, acc[mb][nb], 0, 0, 0);
                acc[mb][nb] = __builtin_amdgcn_mfma_f32_16x16x32_bf16(afl[mb], bfh, acc[mb][nb], 0, 0, 0);
                acc[mb][nb] = __builtin_amdgcn_mfma_f32_16x16x32_bf16(afh[mb], bfl, acc[mb][nb], 0, 0, 0);
            }
        }
        __syncthreads();
    }

    // ---- epilogue: C layout col=lane&15, row=4*(lane>>4)+reg
    #pragma unroll
    for (int nb = 0; nb < FRN; ++nb) {
        int c = n0 + wn * (TN / 2) + nb * 16 + lr;
        if (c < N) {
            float bv = bias ? bias[c] : 0.0f;
            #pragma unroll
            for (int mb = 0; mb < FRM; ++mb) {
                int rb = m0 + wm * (TM / 2) + mb * 16 + lg * 4;
                #pragma unroll
                for (int i = 0; i < 4; ++i) {
                    size_t idx = (size_t)(rb + i) * N + c;
                    float v = acc[mb][nb][i] + bv;
                    if (act) v = gelu_exact(v);
                    if (resid) v += resid[idx];
                    C[idx] = v;
                }
            }
        }
    }
}

// ---------------------------------------------------------------- attention
// One wave per query row; lane d holds head-dim d. Online softmax.
__global__ void attn_kernel(const float* __restrict__ qkv,
                            float* __restrict__ y) {
    int gw = blockIdx.x * 4 + (threadIdx.x >> 6);
    int lane = threadIdx.x & 63;
    int q = gw & (NT - 1);
    int bh = gw >> 10;
    int h = bh % NH;
    int b = bh / NH;

    const float scale = 0.125f;
    const float* base = qkv + (size_t)b * NT * (3 * Dm);
    int col = h * HD + lane;

    float qv = base[(size_t)q * (3 * Dm) + col] * scale;
    float m = -1e30f, l = 0.0f, acc = 0.0f;
    for (int k = 0; k <= q; ++k) {
        const float* krow = base + (size_t)k * (3 * Dm);
        float kv = krow[Dm + col];
        float s = qv * kv;
        #pragma unroll
        for (int off = 32; off; off >>= 1) s += __shfl_xor(s, off);
        float mn = fmaxf(m, s);
        float alpha = __expf(m - mn);
        float p = __expf(s - mn);
        float vv = krow[2 * Dm + col];
        l = l * alpha + p;
        acc = acc * alpha + p * vv;
        m = mn;
    }
    y[(size_t)(b * NT + q) * Dm + col] = acc / l;
}

// ---------------------------------------------------------------- launch
extern "C" void kernel_launch(void* const* d_in, const int* in_sizes, int n_in,
                              void* d_out, int out_size, void* d_ws, size_t ws_size,
                              hipStream_t stream) {
    const int*   ids    = (const int*)  d_in[0];
    const float* wte    = (const float*)d_in[1];
    const float* wpe    = (const float*)d_in[2];
    const float* ln1_g  = (const float*)d_in[3];
    const float* ln1_b  = (const float*)d_in[4];
    const float* attn_w = (const float*)d_in[5];
    const float* attn_b = (const float*)d_in[6];
    const float* proj_w = (const float*)d_in[7];
    const float* proj_b = (const float*)d_in[8];
    const float* ln2_g  = (const float*)d_in[9];
    const float* ln2_b  = (const float*)d_in[10];
    const float* fc_w   = (const float*)d_in[11];
    const float* fc_b   = (const float*)d_in[12];
    const float* fc2_w  = (const float*)d_in[13];
    const float* fc2_b  = (const float*)d_in[14];
    const float* lnf_g  = (const float*)d_in[15];
    const float* lnf_b  = (const float*)d_in[16];
    float* out = (float*)d_out;

    float* ws  = (float*)d_ws;
    float* x   = ws;                           // [2048][768]
    float* h   = x   + (size_t)MROWS * Dm;     // [2048][768]
    float* qkv = h   + (size_t)MROWS * Dm;     // [2048][2304]
    float* y   = qkv + (size_t)MROWS * 3 * Dm; // [2048][768]
    float* h4  = y   + (size_t)MROWS * Dm;     // [2048][3072]

    embed_kernel<<<MROWS, 256, 0, stream>>>(ids, wte, wpe, x);

    for (int l = 0; l < NL; ++l) {
        ln_kernel<<<MROWS, 256, 0, stream>>>(x, ln1_g + l * Dm, ln1_b + l * Dm, h);
        gemm_mfma<128, 128, false><<<dim3(3 * Dm / 128, MROWS / 128), 256, 0, stream>>>(
            h, attn_w + (size_t)l * Dm * 3 * Dm, attn_b + (size_t)l * 3 * Dm,
            nullptr, qkv, MROWS, Dm, 3 * Dm, 0);
        attn_kernel<<<(NB * NH * NT) / 4, 256, 0, stream>>>(qkv, y);
        // N=768 -> 64x64 tile: 384 blocks keeps all 256 CUs fed
        gemm_mfma<64, 64, false><<<dim3(Dm / 64, MROWS / 64), 256, 0, stream>>>(
            y, proj_w + (size_t)l * Dm * Dm, proj_b + (size_t)l * Dm,
            x, x, MROWS, Dm, Dm, 0);
        ln_kernel<<<MROWS, 256, 0, stream>>>(x, ln2_g + l * Dm, ln2_b + l * Dm, h);
        gemm_mfma<128, 128, false><<<dim3(4 * Dm / 128, MROWS / 128), 256, 0, stream>>>(
            h, fc_w + (size_t)l * Dm * 4 * Dm, fc_b + (size_t)l * 4 * Dm,
            nullptr, h4, MROWS, Dm, 4 * Dm, 1);
        gemm_mfma<64, 64, false><<<dim3(Dm / 64, MROWS / 64), 256, 0, stream>>>(
            h4, fc2_w + (size_t)l * 4 * Dm * Dm, fc2_b + (size_t)l * Dm,
            x, x, MROWS, 4 * Dm, Dm, 0);
    }

    ln_kernel<<<MROWS, 256, 0, stream>>>(x, lnf_g, lnf_b, h);
    gemm_mfma<128, 128, true><<<dim3((NV + 127) / 128, MROWS / 128), 256, 0, stream>>>(
        h, wte, nullptr, nullptr, out, MROWS, Dm, NV, 0);
}

// Round 2
// 5553.016 us; speedup vs baseline: 3.2547x; 3.2547x over previous
//
#include <hip/hip_runtime.h>

#define NL 12
#define Dm 768
#define NH 12
#define HD 64
#define NV 50257
#define NB 2
#define NT 1024
#define MROWS (NB * NT)   // 2048

typedef __attribute__((ext_vector_type(8))) short bf16x8;
typedef __attribute__((ext_vector_type(4))) float f32x4;

// fp32 -> (hi, lo) bf16 split.  hi = truncated top 16 bits (exact),
// lo = round-half-up bf16 of the residual.  Net product error ~2^-16 relative.
__device__ __forceinline__ void split2(float f, unsigned short& h, unsigned short& l) {
    unsigned u = __float_as_uint(f);
    h = (unsigned short)(u >> 16);
    float lf = f - __uint_as_float(u & 0xffff0000u);
    unsigned lu = __float_as_uint(lf);
    l = (unsigned short)((lu + 0x8000u) >> 16);
}

__device__ __forceinline__ float gelu_exact(float v) {
    return 0.5f * v * (1.0f + erff(v * 0.70710678118654752f));
}

union U8 { ushort4 u[2]; bf16x8 v; };

// Load one 16x32 MFMA fragment row slice: lane holds 8 contiguous bf16 at
// k = 8*lg. rowp must be 16B-aligned base of the row (stride 72 ushorts in
// the attn kernel, 36 in the GEMM: both give >= 8B-aligned b64 reads and
// at worst 2-way bank aliasing, which is free on CDNA4).
__device__ __forceinline__ bf16x8 ldfrag(const unsigned short* rowp, int lg) {
    U8 t;
    t.u[0] = *(const ushort4*)(rowp + 8 * lg);
    t.u[1] = *(const ushort4*)(rowp + 8 * lg + 4);
    return t.v;
}

// ---------------------------------------------------------------- embedding
__global__ void embed_kernel(const int* __restrict__ ids,
                             const float* __restrict__ wte,
                             const float* __restrict__ wpe,
                             float* __restrict__ x) {
    int row = blockIdx.x;
    int t = row & (NT - 1);
    int id = ids[row];
    const float* src = wte + (size_t)id * Dm;
    const float* pos = wpe + (size_t)t * Dm;
    float* dst = x + (size_t)row * Dm;
    for (int i = threadIdx.x; i < Dm; i += 256)
        dst[i] = src[i] + pos[i];
}

// ---------------------------------------------------------------- layernorm
__global__ void ln_kernel(const float* __restrict__ x,
                          const float* __restrict__ g,
                          const float* __restrict__ b,
                          float* __restrict__ out) {
    int row = blockIdx.x;
    int tid = threadIdx.x;
    const float* xr = x + (size_t)row * Dm;
    float v0 = xr[tid];
    float v1 = xr[tid + 256];
    float v2 = xr[tid + 512];
    float s = v0 + v1 + v2;
    #pragma unroll
    for (int off = 32; off; off >>= 1) s += __shfl_xor(s, off);
    __shared__ float red[4];
    __shared__ float red2[4];
    int wid = tid >> 6;
    if ((tid & 63) == 0) red[wid] = s;
    __syncthreads();
    float mean = (red[0] + red[1] + red[2] + red[3]) * (1.0f / Dm);
    float d0 = v0 - mean, d1 = v1 - mean, d2 = v2 - mean;
    float sq = d0 * d0 + d1 * d1 + d2 * d2;
    #pragma unroll
    for (int off = 32; off; off >>= 1) sq += __shfl_xor(sq, off);
    if ((tid & 63) == 0) red2[wid] = sq;
    __syncthreads();
    float var = (red2[0] + red2[1] + red2[2] + red2[3]) * (1.0f / Dm);
    float rstd = rsqrtf(var + 1e-5f);
    float* o = out + (size_t)row * Dm;
    o[tid]       = d0 * rstd * g[tid]       + b[tid];
    o[tid + 256] = d1 * rstd * g[tid + 256] + b[tid + 256];
    o[tid + 512] = d2 * rstd * g[tid + 512] + b[tid + 512];
}

// ---------------------------------------------------------------- MFMA GEMM
// C[M,N] = act(A[M,K] @ W + bias) + resid, fp32 in/out, bf16-split compute:
// C ~= Ah*Bh + Al*Bh + Ah*Bl (3 MFMA passes).  Layouts per m89/m92:
//   A frag: row = lane&15, k = 8*(lane>>4)+j (8 contiguous)
//   B frag: col = lane&15, same k map
//   C frag: col = lane&15, row = 4*(lane>>4)+reg
template <int TM, int TN, bool TRANSB>
__global__ __launch_bounds__(256, 3)
void gemm_mfma(const float* __restrict__ A,
               const float* __restrict__ W,
               const float* __restrict__ bias,
               const float* __restrict__ resid,
               float* __restrict__ C,
               int M, int K, int N, int act) {
    constexpr int FRM = TM / 32;
    constexpr int FRN = TN / 32;
    constexpr int CPA = TM / 32;
    constexpr int CPW = TN / 32;
    constexpr int WLD = TN + 4;

    __shared__ __align__(16) unsigned short Ah[TM][36];
    __shared__ __align__(16) unsigned short Al[TM][36];
    __shared__ __align__(16) unsigned short Bh[TN][36];
    __shared__ __align__(16) unsigned short Bl[TN][36];
    __shared__ __align__(16) float Wst[TRANSB ? 4 : 32 * WLD];

    const int tid = threadIdx.x;
    const int lane = tid & 63;
    const int wv = tid >> 6;
    const int wm = wv >> 1, wn = wv & 1;
    const int lr = lane & 15, lg = lane >> 4;
    const int m0 = blockIdx.y * TM;
    const int n0 = blockIdx.x * TN;

    f32x4 acc[FRM][FRN];
    #pragma unroll
    for (int i = 0; i < FRM; ++i)
        #pragma unroll
        for (int j = 0; j < FRN; ++j)
            #pragma unroll
            for (int e = 0; e < 4; ++e) acc[i][j][e] = 0.0f;

    const int ttn = tid & (TN - 1);
    const int tks = (tid / TN) * (TN / 8);

    for (int k0 = 0; k0 < K; k0 += 32) {
        #pragma unroll
        for (int i = 0; i < CPA; ++i) {
            int ci = tid * CPA + i;
            int r = ci >> 3, kc = (ci & 7) << 2;
            float4 v = *(const float4*)(A + (size_t)(m0 + r) * K + k0 + kc);
            ushort4 hh, ll;
            split2(v.x, hh.x, ll.x); split2(v.y, hh.y, ll.y);
            split2(v.z, hh.z, ll.z); split2(v.w, hh.w, ll.w);
            *(ushort4*)&Ah[r][kc] = hh;
            *(ushort4*)&Al[r][kc] = ll;
        }
        if constexpr (TRANSB) {
            #pragma unroll
            for (int i = 0; i < CPW; ++i) {
                int ci = tid * CPW + i;
                int r = ci >> 3, kc = (ci & 7) << 2;
                float4 v = make_float4(0.f, 0.f, 0.f, 0.f);
                if (n0 + r < N)
                    v = *(const float4*)(W + (size_t)(n0 + r) * K + k0 + kc);
                ushort4 hh, ll;
                split2(v.x, hh.x, ll.x); split2(v.y, hh.y, ll.y);
                split2(v.z, hh.z, ll.z); split2(v.w, hh.w, ll.w);
                *(ushort4*)&Bh[r][kc] = hh;
                *(ushort4*)&Bl[r][kc] = ll;
            }
            __syncthreads();
        } else {
            #pragma unroll
            for (int i = 0; i < CPW; ++i) {
                int ci = tid * CPW + i;
                int kk = ci / (TN / 4);
                int nc = (ci % (TN / 4)) << 2;
                *(float4*)&Wst[kk * WLD + nc] =
                    *(const float4*)(W + (size_t)(k0 + kk) * N + n0 + nc);
            }
            __syncthreads();
            #pragma unroll
            for (int j4 = 0; j4 < TN / 32; ++j4) {
                ushort4 hh, ll;
                float w0 = Wst[(tks + j4 * 4 + 0) * WLD + ttn];
                float w1 = Wst[(tks + j4 * 4 + 1) * WLD + ttn];
                float w2 = Wst[(tks + j4 * 4 + 2) * WLD + ttn];
                float w3 = Wst[(tks + j4 * 4 + 3) * WLD + ttn];
                split2(w0, hh.x, ll.x); split2(w1, hh.y, ll.y);
                split2(w2, hh.z, ll.z); split2(w3, hh.w, ll.w);
                *(ushort4*)&Bh[ttn][tks + j4 * 4] = hh;
                *(ushort4*)&Bl[ttn][tks + j4 * 4] = ll;
            }
            __syncthreads();
        }

        bf16x8 afh[FRM], afl[FRM];
        #pragma unroll
        for (int mb = 0; mb < FRM; ++mb) {
            int r = wm * (TM / 2) + mb * 16 + lr;
            afh[mb] = ldfrag(&Ah[r][0], lg);
            afl[mb] = ldfrag(&Al[r][0], lg);
        }
        #pragma unroll
        for (int nb = 0; nb < FRN; ++nb) {
            int cB = wn * (TN / 2) + nb * 16 + lr;
            bf16x8 bfh = ldfrag(&Bh[cB][0], lg);
            bf16x8 bfl = ldfrag(&Bl[cB][0], lg);
            #pragma unroll
            for (int mb = 0; mb < FRM; ++mb) {
                acc[mb][nb] = __builtin_amdgcn_mfma_f32_16x16x32_bf16(afh[mb], bfh, acc[mb][nb], 0, 0, 0);
                acc[mb][nb] = __builtin_amdgcn_mfma_f32_16x16x32_bf16(afl[mb], bfh, acc[mb][nb], 0, 0, 0);
                acc[mb][nb] = __builtin_amdgcn_mfma_f32_16x16x32_bf16(afh[mb], bfl, acc[mb][nb], 0, 0, 0);
            }
        }
        __syncthreads();
    }

    #pragma unroll
    for (int nb = 0; nb < FRN; ++nb) {
        int c = n0 + wn * (TN / 2) + nb * 16 + lr;
        if (c < N) {
            float bv = bias ? bias[c] : 0.0f;
            #pragma unroll
            for (int mb = 0; mb < FRM; ++mb) {
                int rb = m0 + wm * (TM / 2) + mb * 16 + lg * 4;
                #pragma unroll
                for (int i = 0; i < 4; ++i) {
                    size_t idx = (size_t)(rb + i) * N + c;
                    float v = acc[mb][nb][i] + bv;
                    if (act) v = gelu_exact(v);
                    if (resid) v += resid[idx];
                    C[idx] = v;
                }
            }
        }
    }
}

// ---------------------------------------------------------------- attention
// Flash attention, bf16-split MFMA.  Block = 4 waves; one (b,h) x 64-query
// tile per block; k-tiles of 64.  Wave w owns q rows [q0+16w, q0+16w+16).
// QK^T: A=Q (rows q, contr d), B=K (cols k-row, contr d), 3-pass split.
// Online softmax in registers (16-lane shfl reduces; S layout col=k,row=q).
// P round-trips through LDS (split) to become the PV A operand; V is staged
// transposed (Vt[d][k]) so PV B-frags read 8 contiguous k per lane.
__global__ __launch_bounds__(256, 2)
void attn_mfma(const float* __restrict__ qkv, float* __restrict__ y) {
    __shared__ __align__(16) unsigned short Kh[64][72], Kl[64][72];
    __shared__ __align__(16) unsigned short Vth[64][72], Vtl[64][72];
    __shared__ __align__(16) unsigned short Ph[64][72], Pl[64][72];

    const int tid = threadIdx.x;
    const int lane = tid & 63;
    const int w = tid >> 6;
    const int lr = lane & 15, lg = lane >> 4;
    const int qt = (int)(gridDim.x - 1 - blockIdx.x);   // heavy tiles first
    const int bh = blockIdx.y;
    const int h = bh % NH, b = bh / NH;
    const int q0 = qt * 64;
    const float scale = 0.125f;   // 1/sqrt(64)

    const float* base = qkv + (size_t)b * NT * (3 * Dm);

    // ---- Q fragments for this wave's 16 rows (scale folded in, split)
    bf16x8 qh[2], ql[2];
    {
        const int qrow = q0 + w * 16 + lr;
        const float* qp = base + (size_t)qrow * (3 * Dm) + h * HD + lg * 8;
        #pragma unroll
        for (int ks = 0; ks < 2; ++ks) {
            float4 x0 = *(const float4*)(qp + 32 * ks);
            float4 x1 = *(const float4*)(qp + 32 * ks + 4);
            U8 th, tl;
            split2(x0.x * scale, th.u[0].x, tl.u[0].x);
            split2(x0.y * scale, th.u[0].y, tl.u[0].y);
            split2(x0.z * scale, th.u[0].z, tl.u[0].z);
            split2(x0.w * scale, th.u[0].w, tl.u[0].w);
            split2(x1.x * scale, th.u[1].x, tl.u[1].x);
            split2(x1.y * scale, th.u[1].y, tl.u[1].y);
            split2(x1.z * scale, th.u[1].z, tl.u[1].z);
            split2(x1.w * scale, th.u[1].w, tl.u[1].w);
            qh[ks] = th.v; ql[ks] = tl.v;
        }
    }

    f32x4 yacc[4];
    #pragma unroll
    for (int df = 0; df < 4; ++df)
        #pragma unroll
        for (int e = 0; e < 4; ++e) yacc[df][e] = 0.0f;
    float m[4] = {-1e30f, -1e30f, -1e30f, -1e30f};
    float lsum[4] = {0.0f, 0.0f, 0.0f, 0.0f};

    const int skr = tid >> 4;            // staging: k-row sub-index 0..15
    const int sd4 = (tid & 15) << 2;     // staging: d chunk 0..60

    for (int kt = 0; kt <= qt; ++kt) {
        const int kt0 = kt * 64;
        __syncthreads();   // previous iteration's LDS reads done
        // ---- stage K (row-major) and V (transposed), both split
        #pragma unroll
        for (int i = 0; i < 4; ++i) {
            int kr = i * 16 + skr;
            const float* kp = base + (size_t)(kt0 + kr) * (3 * Dm) + Dm + h * HD + sd4;
            float4 kv = *(const float4*)kp;
            ushort4 hh, ll;
            split2(kv.x, hh.x, ll.x); split2(kv.y, hh.y, ll.y);
            split2(kv.z, hh.z, ll.z); split2(kv.w, hh.w, ll.w);
            *(ushort4*)&Kh[kr][sd4] = hh;
            *(ushort4*)&Kl[kr][sd4] = ll;
            float4 vv = *(const float4*)(kp + Dm);
            unsigned short vh, vl;
            split2(vv.x, vh, vl); Vth[sd4 + 0][kr] = vh; Vtl[sd4 + 0][kr] = vl;
            split2(vv.y, vh, vl); Vth[sd4 + 1][kr] = vh; Vtl[sd4 + 1][kr] = vl;
            split2(vv.z, vh, vl); Vth[sd4 + 2][kr] = vh; Vtl[sd4 + 2][kr] = vl;
            split2(vv.w, vh, vl); Vth[sd4 + 3][kr] = vh; Vtl[sd4 + 3][kr] = vl;
        }
        __syncthreads();

        // ---- S = Q K^T (3-pass split), S[q=4lg+i][k=nb*16+lr]
        f32x4 s[4];
        #pragma unroll
        for (int nb = 0; nb < 4; ++nb)
            #pragma unroll
            for (int e = 0; e < 4; ++e) s[nb][e] = 0.0f;
        #pragma unroll
        for (int nb = 0; nb < 4; ++nb) {
            #pragma unroll
            for (int ks = 0; ks < 2; ++ks) {
                bf16x8 kfh = ldfrag(&Kh[nb * 16 + lr][32 * ks], lg);
                bf16x8 kfl = ldfrag(&Kl[nb * 16 + lr][32 * ks], lg);
                s[nb] = __builtin_amdgcn_mfma_f32_16x16x32_bf16(qh[ks], kfh, s[nb], 0, 0, 0);
                s[nb] = __builtin_amdgcn_mfma_f32_16x16x32_bf16(ql[ks], kfh, s[nb], 0, 0, 0);
                s[nb] = __builtin_amdgcn_mfma_f32_16x16x32_bf16(qh[ks], kfl, s[nb], 0, 0, 0);
            }
        }

        // ---- causal mask (only the diagonal tile needs it)
        if (kt == qt) {
            #pragma unroll
            for (int nb = 0; nb < 4; ++nb) {
                int kg = kt0 + nb * 16 + lr;
                #pragma unroll
                for (int i = 0; i < 4; ++i) {
                    int qg = q0 + w * 16 + 4 * lg + i;
                    if (kg > qg) s[nb][i] = -1e30f;
                }
            }
        }

        // ---- online softmax (rows live in 16-lane groups)
        float alpha[4];
        #pragma unroll
        for (int i = 0; i < 4; ++i) {
            float mt = fmaxf(fmaxf(s[0][i], s[1][i]), fmaxf(s[2][i], s[3][i]));
            #pragma unroll
            for (int off = 1; off < 16; off <<= 1) mt = fmaxf(mt, __shfl_xor(mt, off));
            float mn = fmaxf(m[i], mt);
            alpha[i] = __expf(m[i] - mn);
            m[i] = mn;
            float rs = 0.0f;
            #pragma unroll
            for (int nb = 0; nb < 4; ++nb) {
                float p = __expf(s[nb][i] - mn);
                s[nb][i] = p;
                rs += p;
            }
            #pragma unroll
            for (int off = 1; off < 16; off <<= 1) rs += __shfl_xor(rs, off);
            lsum[i] = lsum[i] * alpha[i] + rs;
        }

        // ---- write P (split) into this wave's private LDS rows
        #pragma unroll
        for (int nb = 0; nb < 4; ++nb) {
            #pragma unroll
            for (int i = 0; i < 4; ++i) {
                unsigned short hh, ll;
                split2(s[nb][i], hh, ll);
                Ph[w * 16 + 4 * lg + i][nb * 16 + lr] = hh;
                Pl[w * 16 + 4 * lg + i][nb * 16 + lr] = ll;
            }
        }
        __syncthreads();

        // ---- rescale running y, then y += P V (3-pass split)
        #pragma unroll
        for (int df = 0; df < 4; ++df)
            #pragma unroll
            for (int i = 0; i < 4; ++i) yacc[df][i] *= alpha[i];
        #pragma unroll
        for (int ks = 0; ks < 2; ++ks) {
            bf16x8 pah = ldfrag(&Ph[w * 16 + lr][32 * ks], lg);
            bf16x8 pal = ldfrag(&Pl[w * 16 + lr][32 * ks], lg);
            #pragma unroll
            for (int df = 0; df < 4; ++df) {
                bf16x8 vfh = ldfrag(&Vth[df * 16 + lr][32 * ks], lg);
                bf16x8 vfl = ldfrag(&Vtl[df * 16 + lr][32 * ks], lg);
                yacc[df] = __builtin_amdgcn_mfma_f32_16x16x32_bf16(pah, vfh, yacc[df], 0, 0, 0);
                yacc[df] = __builtin_amdgcn_mfma_f32_16x16x32_bf16(pal, vfh, yacc[df], 0, 0, 0);
                yacc[df] = __builtin_amdgcn_mfma_f32_16x16x32_bf16(pah, vfl, yacc[df], 0, 0, 0);
            }
        }
    }

    // ---- epilogue: y /= l, write [row][h*64+d]
    #pragma unroll
    for (int i = 0; i < 4; ++i) {
        float inv = 1.0f / lsum[i];
        int qg = q0 + w * 16 + 4 * lg + i;
        float* yr = y + (size_t)(b * NT + qg) * Dm + h * HD;
        #pragma unroll
        for (int df = 0; df < 4; ++df)
            yr[df * 16 + lr] = yacc[df][i] * inv;
    }
}

// ---------------------------------------------------------------- launch
extern "C" void kernel_launch(void* const* d_in, const int* in_sizes, int n_in,
                              void* d_out, int out_size, void* d_ws, size_t ws_size,
                              hipStream_t stream) {
    const int*   ids    = (const int*)  d_in[0];
    const float* wte    = (const float*)d_in[1];
    const float* wpe    = (const float*)d_in[2];
    const float* ln1_g  = (const float*)d_in[3];
    const float* ln1_b  = (const float*)d_in[4];
    const float* attn_w = (const float*)d_in[5];
    const float* attn_b = (const float*)d_in[6];
    const float* proj_w = (const float*)d_in[7];
    const float* proj_b = (const float*)d_in[8];
    const float* ln2_g  = (const float*)d_in[9];
    const float* ln2_b  = (const float*)d_in[10];
    const float* fc_w   = (const float*)d_in[11];
    const float* fc_b   = (const float*)d_in[12];
    const float* fc2_w  = (const float*)d_in[13];
    const float* fc2_b  = (const float*)d_in[14];
    const float* lnf_g  = (const float*)d_in[15];
    const float* lnf_b  = (const float*)d_in[16];
    float* out = (float*)d_out;

    float* ws  = (float*)d_ws;
    float* x   = ws;                           // [2048][768]
    float* h   = x   + (size_t)MROWS * Dm;     // [2048][768]
    float* qkv = h   + (size_t)MROWS * Dm;     // [2048][2304]
    float* y   = qkv + (size_t)MROWS * 3 * Dm; // [2048][768]
    float* h4  = y   + (size_t)MROWS * Dm;     // [2048][3072]

    embed_kernel<<<MROWS, 256, 0, stream>>>(ids, wte, wpe, x);

    for (int l = 0; l < NL; ++l) {
        ln_kernel<<<MROWS, 256, 0, stream>>>(x, ln1_g + l * Dm, ln1_b + l * Dm, h);
        gemm_mfma<128, 128, false><<<dim3(3 * Dm / 128, MROWS / 128), 256, 0, stream>>>(
            h, attn_w + (size_t)l * Dm * 3 * Dm, attn_b + (size_t)l * 3 * Dm,
            nullptr, qkv, MROWS, Dm, 3 * Dm, 0);
        attn_mfma<<<dim3(NT / 64, NB * NH), 256, 0, stream>>>(qkv, y);
        gemm_mfma<64, 64, false><<<dim3(Dm / 64, MROWS / 64), 256, 0, stream>>>(
            y, proj_w + (size_t)l * Dm * Dm, proj_b + (size_t)l * Dm,
            x, x, MROWS, Dm, Dm, 0);
        ln_kernel<<<MROWS, 256, 0, stream>>>(x, ln2_g + l * Dm, ln2_b + l * Dm, h);
        gemm_mfma<128, 128, false><<<dim3(4 * Dm / 128, MROWS / 128), 256, 0, stream>>>(
            h, fc_w + (size_t)l * Dm * 4 * Dm, fc_b + (size_t)l * 4 * Dm,
            nullptr, h4, MROWS, Dm, 4 * Dm, 1);
        gemm_mfma<64, 64, false><<<dim3(Dm / 64, MROWS / 64), 256, 0, stream>>>(
            h4, fc2_w + (size_t)l * 4 * Dm * Dm, fc2_b + (size_t)l * Dm,
            x, x, MROWS, 4 * Dm, Dm, 0);
    }

    ln_kernel<<<MROWS, 256, 0, stream>>>(x, lnf_g, lnf_b, h);
    gemm_mfma<128, 128, true><<<dim3((NV + 127) / 128, MROWS / 128), 256, 0, stream>>>(
        h, wte, nullptr, nullptr, out, MROWS, Dm, NV, 0);
}

// Round 5
// 4946.481 us; speedup vs baseline: 3.6538x; 1.1226x over previous
//
#include <hip/hip_runtime.h>

#define NL 12
#define Dm 768
#define NH 12
#define HD 64
#define NV 50257
#define NB 2
#define NT 1024
#define MROWS (NB * NT)   // 2048

typedef __attribute__((ext_vector_type(8))) short bf16x8;
typedef __attribute__((ext_vector_type(4))) float f32x4;

// fp32 -> (hi, lo) bf16 split.  hi = truncated top 16 bits (exact),
// lo = round-half-up bf16 of the residual.  Net product error ~2^-16 relative.
__device__ __forceinline__ void split2(float f, unsigned short& h, unsigned short& l) {
    unsigned u = __float_as_uint(f);
    h = (unsigned short)(u >> 16);
    float lf = f - __uint_as_float(u & 0xffff0000u);
    unsigned lu = __float_as_uint(lf);
    l = (unsigned short)((lu + 0x8000u) >> 16);
}

__device__ __forceinline__ float gelu_exact(float v) {
    return 0.5f * v * (1.0f + erff(v * 0.70710678118654752f));
}

union U8 { ushort4 u[2]; bf16x8 v; };

// Load one 16x32 MFMA fragment slice: lane holds 8 contiguous bf16 at k=8*lg.
// rowp must be 8B-aligned.  Row strides used (36 or 68 ushorts = 18/34 dwords)
// give all-distinct bank residues over lr=0..15 (gcd(stride_dw,32)==2).
__device__ __forceinline__ bf16x8 ldfrag(const unsigned short* rowp, int lg) {
    U8 t;
    t.u[0] = *(const ushort4*)(rowp + 8 * lg);
    t.u[1] = *(const ushort4*)(rowp + 8 * lg + 4);
    return t.v;
}

// ---------------------------------------------------------------- pre-split
// W[K,N] fp32 row-major -> Wh/Wl [N,K] bf16 row-major (transpose + split).
__global__ void wtsplit_kernel(const float* __restrict__ W,
                               unsigned short* __restrict__ Wh,
                               unsigned short* __restrict__ Wl,
                               int K, int N) {
    __shared__ float T[32][33];
    const int k0 = blockIdx.x * 32, n0 = blockIdx.y * 32;
    const int t = threadIdx.x;
    const int r = t >> 3, c4 = (t & 7) << 2;
    float4 v = *(const float4*)(W + (size_t)(k0 + r) * N + n0 + c4);
    T[r][c4 + 0] = v.x; T[r][c4 + 1] = v.y; T[r][c4 + 2] = v.z; T[r][c4 + 3] = v.w;
    __syncthreads();
    ushort4 hh, ll;
    split2(T[c4 + 0][r], hh.x, ll.x);
    split2(T[c4 + 1][r], hh.y, ll.y);
    split2(T[c4 + 2][r], hh.z, ll.z);
    split2(T[c4 + 3][r], hh.w, ll.w);
    *(ushort4*)(Wh + (size_t)(n0 + r) * K + k0 + c4) = hh;
    *(ushort4*)(Wl + (size_t)(n0 + r) * K + k0 + c4) = ll;
}

// Elementwise split (wte is already [N,K]).
__global__ void wsplit_kernel(const float* __restrict__ W,
                              unsigned short* __restrict__ Wh,
                              unsigned short* __restrict__ Wl, size_t n4) {
    size_t i = (size_t)blockIdx.x * 256 + threadIdx.x;
    if (i >= n4) return;
    float4 v = *(const float4*)(W + i * 4);
    ushort4 hh, ll;
    split2(v.x, hh.x, ll.x); split2(v.y, hh.y, ll.y);
    split2(v.z, hh.z, ll.z); split2(v.w, hh.w, ll.w);
    *(ushort4*)(Wh + i * 4) = hh;
    *(ushort4*)(Wl + i * 4) = ll;
}

// ---------------------------------------------------------------- embedding
__global__ void embed_kernel(const int* __restrict__ ids,
                             const float* __restrict__ wte,
                             const float* __restrict__ wpe,
                             float* __restrict__ x) {
    int row = blockIdx.x;
    int t = row & (NT - 1);
    int id = ids[row];
    const float* src = wte + (size_t)id * Dm;
    const float* pos = wpe + (size_t)t * Dm;
    float* dst = x + (size_t)row * Dm;
    for (int i = threadIdx.x; i < Dm; i += 256)
        dst[i] = src[i] + pos[i];
}

// ---------------------------------------------------------------- layernorm
// Emits pre-split (hi, lo) bf16 pairs: the next GEMM's A operand.
__global__ void ln_split_kernel(const float* __restrict__ x,
                                const float* __restrict__ g,
                                const float* __restrict__ b,
                                unsigned short* __restrict__ oh,
                                unsigned short* __restrict__ ol) {
    int row = blockIdx.x;
    int tid = threadIdx.x;
    const float* xr = x + (size_t)row * Dm;
    float v0 = xr[tid];
    float v1 = xr[tid + 256];
    float v2 = xr[tid + 512];
    float s = v0 + v1 + v2;
    #pragma unroll
    for (int off = 32; off; off >>= 1) s += __shfl_xor(s, off);
    __shared__ float red[4];
    __shared__ float red2[4];
    int wid = tid >> 6;
    if ((tid & 63) == 0) red[wid] = s;
    __syncthreads();
    float mean = (red[0] + red[1] + red[2] + red[3]) * (1.0f / Dm);
    float d0 = v0 - mean, d1 = v1 - mean, d2 = v2 - mean;
    float sq = d0 * d0 + d1 * d1 + d2 * d2;
    #pragma unroll
    for (int off = 32; off; off >>= 1) sq += __shfl_xor(sq, off);
    if ((tid & 63) == 0) red2[wid] = sq;
    __syncthreads();
    float var = (red2[0] + red2[1] + red2[2] + red2[3]) * (1.0f / Dm);
    float rstd = rsqrtf(var + 1e-5f);
    unsigned short hh, ll;
    size_t o = (size_t)row * Dm;
    split2(d0 * rstd * g[tid]       + b[tid],       hh, ll); oh[o + tid]       = hh; ol[o + tid]       = ll;
    split2(d1 * rstd * g[tid + 256] + b[tid + 256], hh, ll); oh[o + tid + 256] = hh; ol[o + tid + 256] = ll;
    split2(d2 * rstd * g[tid + 512] + b[tid + 512], hh, ll); oh[o + tid + 512] = hh; ol[o + tid + 512] = ll;
}

// ---------------------------------------------------------------- MFMA GEMM
// C[M,N] = act(A @ W^T + bias) + resid.  A pre-split bf16 [M,K] (hi,lo);
// W pre-split bf16 [N,K] (WSPLIT) or fp32 [N,K] split in-kernel (!WSPLIT).
// 3-pass split MFMA: Ah*Wh + Al*Wh + Ah*Wl.  Block = 4 waves (2x2);
// wave tile (TM/2)x(TN/2); 16x16x32 frags.  TM*BK == TN*BK == 4096 so each
// thread stages exactly one 16-ELEMENT (32B) chunk per LDS array per k-step
// (two uint4 global loads -> four 8B LDS writes).
template <int TM, int TN, int BK, bool WSPLIT, bool NGUARD>
__global__ __launch_bounds__(256, 4)
void gemm_ps(const unsigned short* __restrict__ Ahg,
             const unsigned short* __restrict__ Alg,
             const unsigned short* __restrict__ Whg,
             const unsigned short* __restrict__ Wlg,
             const float* __restrict__ Wf,
             const float* __restrict__ bias,
             const float* __restrict__ resid,
             float* __restrict__ C,
             unsigned short* __restrict__ Ch,
             unsigned short* __restrict__ Cl,
             int M, int K, int N, int act) {
    static_assert(TM * BK == 4096 && TN * BK == 4096, "staging map");
    constexpr int FRM = TM / 32;
    constexpr int FRN = TN / 32;
    constexpr int LD = BK + 4;            // 36 or 68 ushorts: conflict-free frags

    __shared__ __align__(16) unsigned short Ahs[TM][LD], Als[TM][LD];
    __shared__ __align__(16) unsigned short Bhs[TN][LD], Bls[TN][LD];

    const int tid = threadIdx.x;
    const int lane = tid & 63;
    const int wv = tid >> 6;
    const int wm = wv >> 1, wn = wv & 1;
    const int lr = lane & 15, lg = lane >> 4;
    const int m0 = blockIdx.y * TM;
    const int n0 = blockIdx.x * TN;

    constexpr int CPR = BK / 16;          // 16-el chunks per row
    const int sr = tid / CPR;
    const int skc = (tid % CPR) * 16;

    f32x4 acc[FRM][FRN];
    #pragma unroll
    for (int i = 0; i < FRM; ++i)
        #pragma unroll
        for (int j = 0; j < FRN; ++j)
            #pragma unroll
            for (int e = 0; e < 4; ++e) acc[i][j][e] = 0.0f;

    for (int k0 = 0; k0 < K; k0 += BK) {
        {   // ---- stage A (hi, lo): 16 elements = 2 x uint4 loads per thread
            size_t ga = (size_t)(m0 + sr) * K + k0 + skc;
            uint4 a0 = *(const uint4*)(Ahg + ga);
            uint4 a1 = *(const uint4*)(Ahg + ga + 8);
            *(uint2*)&Ahs[sr][skc]      = make_uint2(a0.x, a0.y);
            *(uint2*)&Ahs[sr][skc + 4]  = make_uint2(a0.z, a0.w);
            *(uint2*)&Ahs[sr][skc + 8]  = make_uint2(a1.x, a1.y);
            *(uint2*)&Ahs[sr][skc + 12] = make_uint2(a1.z, a1.w);
            uint4 l0 = *(const uint4*)(Alg + ga);
            uint4 l1 = *(const uint4*)(Alg + ga + 8);
            *(uint2*)&Als[sr][skc]      = make_uint2(l0.x, l0.y);
            *(uint2*)&Als[sr][skc + 4]  = make_uint2(l0.z, l0.w);
            *(uint2*)&Als[sr][skc + 8]  = make_uint2(l1.x, l1.y);
            *(uint2*)&Als[sr][skc + 12] = make_uint2(l1.z, l1.w);
        }
        if constexpr (WSPLIT) {
            bool ok = !NGUARD || (n0 + sr < N);
            size_t gb = (size_t)(n0 + sr) * K + k0 + skc;
            uint4 h0 = make_uint4(0, 0, 0, 0), h1 = h0, w0 = h0, w1 = h0;
            if (ok) {
                h0 = *(const uint4*)(Whg + gb);
                h1 = *(const uint4*)(Whg + gb + 8);
                w0 = *(const uint4*)(Wlg + gb);
                w1 = *(const uint4*)(Wlg + gb + 8);
            }
            *(uint2*)&Bhs[sr][skc]      = make_uint2(h0.x, h0.y);
            *(uint2*)&Bhs[sr][skc + 4]  = make_uint2(h0.z, h0.w);
            *(uint2*)&Bhs[sr][skc + 8]  = make_uint2(h1.x, h1.y);
            *(uint2*)&Bhs[sr][skc + 12] = make_uint2(h1.z, h1.w);
            *(uint2*)&Bls[sr][skc]      = make_uint2(w0.x, w0.y);
            *(uint2*)&Bls[sr][skc + 4]  = make_uint2(w0.z, w0.w);
            *(uint2*)&Bls[sr][skc + 8]  = make_uint2(w1.x, w1.y);
            *(uint2*)&Bls[sr][skc + 12] = make_uint2(w1.z, w1.w);
        } else {
            // fp32 [N,K] in-kernel split (fallback lm-head)
            #pragma unroll
            for (int i = 0; i < 4; ++i) {
                int ci = tid * 4 + i;
                int r = ci / (BK / 4), kc4 = (ci % (BK / 4)) * 4;
                float4 v = make_float4(0.f, 0.f, 0.f, 0.f);
                if (!NGUARD || n0 + r < N)
                    v = *(const float4*)(Wf + (size_t)(n0 + r) * K + k0 + kc4);
                ushort4 hh, ll;
                split2(v.x, hh.x, ll.x); split2(v.y, hh.y, ll.y);
                split2(v.z, hh.z, ll.z); split2(v.w, hh.w, ll.w);
                *(ushort4*)&Bhs[r][kc4] = hh;
                *(ushort4*)&Bls[r][kc4] = ll;
            }
        }
        __syncthreads();

        #pragma unroll
        for (int ks = 0; ks < BK / 32; ++ks) {
            bf16x8 afh[FRM], afl[FRM];
            #pragma unroll
            for (int mb = 0; mb < FRM; ++mb) {
                int r = wm * (TM / 2) + mb * 16 + lr;
                afh[mb] = ldfrag(&Ahs[r][32 * ks], lg);
                afl[mb] = ldfrag(&Als[r][32 * ks], lg);
            }
            #pragma unroll
            for (int nb = 0; nb < FRN; ++nb) {
                int cB = wn * (TN / 2) + nb * 16 + lr;
                bf16x8 bfh = ldfrag(&Bhs[cB][32 * ks], lg);
                bf16x8 bfl = ldfrag(&Bls[cB][32 * ks], lg);
                #pragma unroll
                for (int mb = 0; mb < FRM; ++mb) {
                    acc[mb][nb] = __builtin_amdgcn_mfma_f32_16x16x32_bf16(afh[mb], bfh, acc[mb][nb], 0, 0, 0);
                    acc[mb][nb] = __builtin_amdgcn_mfma_f32_16x16x32_bf16(afl[mb], bfh, acc[mb][nb], 0, 0, 0);
                    acc[mb][nb] = __builtin_amdgcn_mfma_f32_16x16x32_bf16(afh[mb], bfl, acc[mb][nb], 0, 0, 0);
                }
            }
        }
        __syncthreads();
    }

    // ---- epilogue: C layout col=lane&15, row=4*(lane>>4)+reg
    #pragma unroll
    for (int nb = 0; nb < FRN; ++nb) {
        int c = n0 + wn * (TN / 2) + nb * 16 + lr;
        if (!NGUARD || c < N) {
            float bv = bias ? bias[c] : 0.0f;
            #pragma unroll
            for (int mb = 0; mb < FRM; ++mb) {
                int rb = m0 + wm * (TM / 2) + mb * 16 + lg * 4;
                #pragma unroll
                for (int i = 0; i < 4; ++i) {
                    size_t idx = (size_t)(rb + i) * N + c;
                    float v = acc[mb][nb][i] + bv;
                    if (act) v = gelu_exact(v);
                    if (resid) v += resid[idx];
                    if (Ch) {
                        unsigned short hh, ll;
                        split2(v, hh, ll);
                        Ch[idx] = hh; Cl[idx] = ll;
                    } else {
                        C[idx] = v;
                    }
                }
            }
        }
    }
}

// ---------------------------------------------------------------- attention
// Flash attention, bf16-split MFMA (round-2 verified structure).
// Emits pre-split y (hi, lo) for the proj GEMM's A operand.
__global__ __launch_bounds__(256, 2)
void attn_mfma(const float* __restrict__ qkv,
               unsigned short* __restrict__ yh,
               unsigned short* __restrict__ yl) {
    __shared__ __align__(16) unsigned short Kh[64][68], Kl[64][68];
    __shared__ __align__(16) unsigned short Vth[64][68], Vtl[64][68];
    __shared__ __align__(16) unsigned short Ph[64][68], Pl[64][68];

    const int tid = threadIdx.x;
    const int lane = tid & 63;
    const int w = tid >> 6;
    const int lr = lane & 15, lg = lane >> 4;
    const int qt = (int)(gridDim.x - 1 - blockIdx.x);   // heavy tiles first
    const int bh = blockIdx.y;
    const int h = bh % NH, b = bh / NH;
    const int q0 = qt * 64;
    const float scale = 0.125f;   // 1/sqrt(64)

    const float* base = qkv + (size_t)b * NT * (3 * Dm);

    bf16x8 qh[2], ql[2];
    {
        const int qrow = q0 + w * 16 + lr;
        const float* qp = base + (size_t)qrow * (3 * Dm) + h * HD + lg * 8;
        #pragma unroll
        for (int ks = 0; ks < 2; ++ks) {
            float4 x0 = *(const float4*)(qp + 32 * ks);
            float4 x1 = *(const float4*)(qp + 32 * ks + 4);
            U8 th, tl;
            split2(x0.x * scale, th.u[0].x, tl.u[0].x);
            split2(x0.y * scale, th.u[0].y, tl.u[0].y);
            split2(x0.z * scale, th.u[0].z, tl.u[0].z);
            split2(x0.w * scale, th.u[0].w, tl.u[0].w);
            split2(x1.x * scale, th.u[1].x, tl.u[1].x);
            split2(x1.y * scale, th.u[1].y, tl.u[1].y);
            split2(x1.z * scale, th.u[1].z, tl.u[1].z);
            split2(x1.w * scale, th.u[1].w, tl.u[1].w);
            qh[ks] = th.v; ql[ks] = tl.v;
        }
    }

    f32x4 yacc[4];
    #pragma unroll
    for (int df = 0; df < 4; ++df)
        #pragma unroll
        for (int e = 0; e < 4; ++e) yacc[df][e] = 0.0f;
    float m[4] = {-1e30f, -1e30f, -1e30f, -1e30f};
    float lsum[4] = {0.0f, 0.0f, 0.0f, 0.0f};

    const int skr = tid >> 4;
    const int sd4 = (tid & 15) << 2;

    for (int kt = 0; kt <= qt; ++kt) {
        const int kt0 = kt * 64;
        __syncthreads();
        #pragma unroll
        for (int i = 0; i < 4; ++i) {
            int kr = i * 16 + skr;
            const float* kp = base + (size_t)(kt0 + kr) * (3 * Dm) + Dm + h * HD + sd4;
            float4 kv = *(const float4*)kp;
            ushort4 hh, ll;
            split2(kv.x, hh.x, ll.x); split2(kv.y, hh.y, ll.y);
            split2(kv.z, hh.z, ll.z); split2(kv.w, hh.w, ll.w);
            *(ushort4*)&Kh[kr][sd4] = hh;
            *(ushort4*)&Kl[kr][sd4] = ll;
            float4 vv = *(const float4*)(kp + Dm);
            unsigned short vh, vl;
            split2(vv.x, vh, vl); Vth[sd4 + 0][kr] = vh; Vtl[sd4 + 0][kr] = vl;
            split2(vv.y, vh, vl); Vth[sd4 + 1][kr] = vh; Vtl[sd4 + 1][kr] = vl;
            split2(vv.z, vh, vl); Vth[sd4 + 2][kr] = vh; Vtl[sd4 + 2][kr] = vl;
            split2(vv.w, vh, vl); Vth[sd4 + 3][kr] = vh; Vtl[sd4 + 3][kr] = vl;
        }
        __syncthreads();

        f32x4 s[4];
        #pragma unroll
        for (int nb = 0; nb < 4; ++nb)
            #pragma unroll
            for (int e = 0; e < 4; ++e) s[nb][e] = 0.0f;
        #pragma unroll
        for (int nb = 0; nb < 4; ++nb) {
            #pragma unroll
            for (int ks = 0; ks < 2; ++ks) {
                bf16x8 kfh = ldfrag(&Kh[nb * 16 + lr][32 * ks], lg);
                bf16x8 kfl = ldfrag(&Kl[nb * 16 + lr][32 * ks], lg);
                s[nb] = __builtin_amdgcn_mfma_f32_16x16x32_bf16(qh[ks], kfh, s[nb], 0, 0, 0);
                s[nb] = __builtin_amdgcn_mfma_f32_16x16x32_bf16(ql[ks], kfh, s[nb], 0, 0, 0);
                s[nb] = __builtin_amdgcn_mfma_f32_16x16x32_bf16(qh[ks], kfl, s[nb], 0, 0, 0);
            }
        }

        if (kt == qt) {
            #pragma unroll
            for (int nb = 0; nb < 4; ++nb) {
                int kg = kt0 + nb * 16 + lr;
                #pragma unroll
                for (int i = 0; i < 4; ++i) {
                    int qg = q0 + w * 16 + 4 * lg + i;
                    if (kg > qg) s[nb][i] = -1e30f;
                }
            }
        }

        float alpha[4];
        #pragma unroll
        for (int i = 0; i < 4; ++i) {
            float mt = fmaxf(fmaxf(s[0][i], s[1][i]), fmaxf(s[2][i], s[3][i]));
            #pragma unroll
            for (int off = 1; off < 16; off <<= 1) mt = fmaxf(mt, __shfl_xor(mt, off));
            float mn = fmaxf(m[i], mt);
            alpha[i] = __expf(m[i] - mn);
            m[i] = mn;
            float rs = 0.0f;
            #pragma unroll
            for (int nb = 0; nb < 4; ++nb) {
                float p = __expf(s[nb][i] - mn);
                s[nb][i] = p;
                rs += p;
            }
            #pragma unroll
            for (int off = 1; off < 16; off <<= 1) rs += __shfl_xor(rs, off);
            lsum[i] = lsum[i] * alpha[i] + rs;
        }

        #pragma unroll
        for (int nb = 0; nb < 4; ++nb) {
            #pragma unroll
            for (int i = 0; i < 4; ++i) {
                unsigned short hh, ll;
                split2(s[nb][i], hh, ll);
                Ph[w * 16 + 4 * lg + i][nb * 16 + lr] = hh;
                Pl[w * 16 + 4 * lg + i][nb * 16 + lr] = ll;
            }
        }
        __syncthreads();

        #pragma unroll
        for (int df = 0; df < 4; ++df)
            #pragma unroll
            for (int i = 0; i < 4; ++i) yacc[df][i] *= alpha[i];
        #pragma unroll
        for (int ks = 0; ks < 2; ++ks) {
            bf16x8 pah = ldfrag(&Ph[w * 16 + lr][32 * ks], lg);
            bf16x8 pal = ldfrag(&Pl[w * 16 + lr][32 * ks], lg);
            #pragma unroll
            for (int df = 0; df < 4; ++df) {
                bf16x8 vfh = ldfrag(&Vth[df * 16 + lr][32 * ks], lg);
                bf16x8 vfl = ldfrag(&Vtl[df * 16 + lr][32 * ks], lg);
                yacc[df] = __builtin_amdgcn_mfma_f32_16x16x32_bf16(pah, vfh, yacc[df], 0, 0, 0);
                yacc[df] = __builtin_amdgcn_mfma_f32_16x16x32_bf16(pal, vfh, yacc[df], 0, 0, 0);
                yacc[df] = __builtin_amdgcn_mfma_f32_16x16x32_bf16(pah, vfl, yacc[df], 0, 0, 0);
            }
        }
    }

    #pragma unroll
    for (int i = 0; i < 4; ++i) {
        float inv = 1.0f / lsum[i];
        int qg = q0 + w * 16 + 4 * lg + i;
        size_t o = (size_t)(b * NT + qg) * Dm + h * HD;
        #pragma unroll
        for (int df = 0; df < 4; ++df) {
            unsigned short hh, ll;
            split2(yacc[df][i] * inv, hh, ll);
            yh[o + df * 16 + lr] = hh;
            yl[o + df * 16 + lr] = ll;
        }
    }
}

// ---------------------------------------------------------------- launch
extern "C" void kernel_launch(void* const* d_in, const int* in_sizes, int n_in,
                              void* d_out, int out_size, void* d_ws, size_t ws_size,
                              hipStream_t stream) {
    const int*   ids    = (const int*)  d_in[0];
    const float* wte    = (const float*)d_in[1];
    const float* wpe    = (const float*)d_in[2];
    const float* ln1_g  = (const float*)d_in[3];
    const float* ln1_b  = (const float*)d_in[4];
    const float* attn_w = (const float*)d_in[5];
    const float* attn_b = (const float*)d_in[6];
    const float* proj_w = (const float*)d_in[7];
    const float* proj_b = (const float*)d_in[8];
    const float* ln2_g  = (const float*)d_in[9];
    const float* ln2_b  = (const float*)d_in[10];
    const float* fc_w   = (const float*)d_in[11];
    const float* fc_b   = (const float*)d_in[12];
    const float* fc2_w  = (const float*)d_in[13];
    const float* fc2_b  = (const float*)d_in[14];
    const float* lnf_g  = (const float*)d_in[15];
    const float* lnf_b  = (const float*)d_in[16];
    float* out = (float*)d_out;

    typedef unsigned short us;
    char* base = (char*)d_ws;
    size_t off = 0;
    auto alloc = [&](size_t bytes) -> void* {
        off = (off + 255) & ~(size_t)255;
        void* r = base + off;
        off += bytes;
        return r;
    };

    // activations
    float* x    = (float*)alloc((size_t)MROWS * Dm * 4);
    float* qkvb = (float*)alloc((size_t)MROWS * 3 * Dm * 4);
    us* hh  = (us*)alloc((size_t)MROWS * Dm * 2);
    us* hl  = (us*)alloc((size_t)MROWS * Dm * 2);
    us* yh  = (us*)alloc((size_t)MROWS * Dm * 2);
    us* yl  = (us*)alloc((size_t)MROWS * Dm * 2);
    us* h4h = (us*)alloc((size_t)MROWS * 4 * Dm * 2);
    us* h4l = (us*)alloc((size_t)MROWS * 4 * Dm * 2);

    const size_t EQ = (size_t)Dm * 3 * Dm;   // per-layer qkv weight elems
    const size_t EP = (size_t)Dm * Dm;
    const size_t EF = (size_t)Dm * 4 * Dm;
    const size_t EWTE = (size_t)NV * Dm;
    const size_t full_need = off + 2 * 2 * (EWTE + NL * (EQ + EP + EF + EF)) + 64 * 256;
    const bool full = ws_size >= full_need;

    us *qWh, *qWl, *pWh, *pWl, *fWh, *fWl, *f2Wh, *f2Wl, *wteh = nullptr, *wtel = nullptr;
    if (full) {
        qWh  = (us*)alloc(NL * EQ * 2);  qWl  = (us*)alloc(NL * EQ * 2);
        pWh  = (us*)alloc(NL * EP * 2);  pWl  = (us*)alloc(NL * EP * 2);
        fWh  = (us*)alloc(NL * EF * 2);  fWl  = (us*)alloc(NL * EF * 2);
        f2Wh = (us*)alloc(NL * EF * 2);  f2Wl = (us*)alloc(NL * EF * 2);
        wteh = (us*)alloc(EWTE * 2);     wtel = (us*)alloc(EWTE * 2);
        for (int l = 0; l < NL; ++l) {
            wtsplit_kernel<<<dim3(Dm / 32, 3 * Dm / 32), 256, 0, stream>>>(
                attn_w + l * EQ, qWh + l * EQ, qWl + l * EQ, Dm, 3 * Dm);
            wtsplit_kernel<<<dim3(Dm / 32, Dm / 32), 256, 0, stream>>>(
                proj_w + l * EP, pWh + l * EP, pWl + l * EP, Dm, Dm);
            wtsplit_kernel<<<dim3(Dm / 32, 4 * Dm / 32), 256, 0, stream>>>(
                fc_w + l * EF, fWh + l * EF, fWl + l * EF, Dm, 4 * Dm);
            wtsplit_kernel<<<dim3(4 * Dm / 32, Dm / 32), 256, 0, stream>>>(
                fc2_w + l * EF, f2Wh + l * EF, f2Wl + l * EF, 4 * Dm, Dm);
        }
        size_t n4 = EWTE / 4;
        wsplit_kernel<<<(unsigned)((n4 + 255) / 256), 256, 0, stream>>>(wte, wteh, wtel, n4);
    } else {
        // rotating per-layer buffers; lm-head splits wte in-kernel
        qWh  = (us*)alloc(EQ * 2);  qWl  = (us*)alloc(EQ * 2);
        pWh  = (us*)alloc(EP * 2);  pWl  = (us*)alloc(EP * 2);
        fWh  = (us*)alloc(EF * 2);  fWl  = (us*)alloc(EF * 2);
        f2Wh = (us*)alloc(EF * 2);  f2Wl = (us*)alloc(EF * 2);
    }

    embed_kernel<<<MROWS, 256, 0, stream>>>(ids, wte, wpe, x);

    for (int l = 0; l < NL; ++l) {
        size_t oq = full ? l * EQ : 0, op = full ? l * EP : 0, of = full ? l * EF : 0;
        if (!full) {
            wtsplit_kernel<<<dim3(Dm / 32, 3 * Dm / 32), 256, 0, stream>>>(
                attn_w + l * EQ, qWh, qWl, Dm, 3 * Dm);
            wtsplit_kernel<<<dim3(Dm / 32, Dm / 32), 256, 0, stream>>>(
                proj_w + l * EP, pWh, pWl, Dm, Dm);
            wtsplit_kernel<<<dim3(Dm / 32, 4 * Dm / 32), 256, 0, stream>>>(
                fc_w + l * EF, fWh, fWl, Dm, 4 * Dm);
            wtsplit_kernel<<<dim3(4 * Dm / 32, Dm / 32), 256, 0, stream>>>(
                fc2_w + l * EF, f2Wh, f2Wl, 4 * Dm, Dm);
        }
        ln_split_kernel<<<MROWS, 256, 0, stream>>>(x, ln1_g + l * Dm, ln1_b + l * Dm, hh, hl);
        gemm_ps<128, 128, 32, true, false><<<dim3(3 * Dm / 128, MROWS / 128), 256, 0, stream>>>(
            hh, hl, qWh + oq, qWl + oq, nullptr, attn_b + (size_t)l * 3 * Dm,
            nullptr, qkvb, nullptr, nullptr, MROWS, Dm, 3 * Dm, 0);
        attn_mfma<<<dim3(NT / 64, NB * NH), 256, 0, stream>>>(qkvb, yh, yl);
        gemm_ps<64, 64, 64, true, false><<<dim3(Dm / 64, MROWS / 64), 256, 0, stream>>>(
            yh, yl, pWh + op, pWl + op, nullptr, proj_b + (size_t)l * Dm,
            x, x, nullptr, nullptr, MROWS, Dm, Dm, 0);
        ln_split_kernel<<<MROWS, 256, 0, stream>>>(x, ln2_g + l * Dm, ln2_b + l * Dm, hh, hl);
        gemm_ps<128, 128, 32, true, false><<<dim3(4 * Dm / 128, MROWS / 128), 256, 0, stream>>>(
            hh, hl, fWh + of, fWl + of, nullptr, fc_b + (size_t)l * 4 * Dm,
            nullptr, nullptr, h4h, h4l, MROWS, Dm, 4 * Dm, 1);
        gemm_ps<64, 64, 64, true, false><<<dim3(Dm / 64, MROWS / 64), 256, 0, stream>>>(
            h4h, h4l, f2Wh + of, f2Wl + of, nullptr, fc2_b + (size_t)l * Dm,
            x, x, nullptr, nullptr, MROWS, 4 * Dm, Dm, 0);
    }

    ln_split_kernel<<<MROWS, 256, 0, stream>>>(x, lnf_g, lnf_b, hh, hl);
    if (full) {
        gemm_ps<128, 128, 32, true, true><<<dim3((NV + 127) / 128, MROWS / 128), 256, 0, stream>>>(
            hh, hl, wteh, wtel, nullptr, nullptr,
            nullptr, out, nullptr, nullptr, MROWS, Dm, NV, 0);
    } else {
        gemm_ps<128, 128, 32, false, true><<<dim3((NV + 127) / 128, MROWS / 128), 256, 0, stream>>>(
            hh, hl, nullptr, nullptr, wte, nullptr,
            nullptr, out, nullptr, nullptr, MROWS, Dm, NV, 0);
    }
}